// Round 2
// baseline (136.528 us; speedup 1.0000x reference)
//
#include <hip/hip_runtime.h>

// ConvTranspose3d(3->16, k=3, s=2, p=1) + per-channel norm + 2x avgpool2 fused.
// y (32,16,63,63,63) never materialized. out = 4^3-pooled normalized y -> (32,16,15,15,15).
// Each thread: one 4x4x4 y-block for TWO output channels (x loads amortized).
// Loads are unconditional with clamped indices; clamp garbage flows only into
// y[*==3] elements, which edge threads zero before stats anyway.

#define N_BATCH 32
#define C_OUT 16
#define P_OUT 15
#define COUNT_Y 8001504.0f  // 32 * 63^3
#define TOTAL_OUT (N_BATCH * C_OUT * P_OUT * P_OUT * P_OUT)  // 1,728,000

// tap tables: local output offset lo -> (k, i_local) pairs
// lo=0: (1,0)   lo=1: (2,0),(0,1)   lo=2: (1,1)   lo=3: (2,1),(0,2)
constexpr int NPAIR[4]  = {1, 2, 1, 2};
constexpr int PK[4][2]  = {{1, 1}, {2, 0}, {1, 1}, {2, 0}};
constexpr int PI[4][2]  = {{0, 0}, {0, 1}, {1, 1}, {1, 2}};

__global__ __launch_bounds__(256, 2) void convt_pool_stats(
    const float* __restrict__ x,        // [32][3][32][32][32]
    const float* __restrict__ w,        // [3][16][3][3][3]
    float* __restrict__ pool,           // d_out: [32][16][15][15][15] raw 4^3 sums
    float* __restrict__ partials)       // ws: sums [8192], sumsq [8192], layout [co][n][bd]
{
    const int bd  = blockIdx.x;         // 0..15
    const int cop = blockIdx.y;         // 0..7 -> co = 2*cop + c2
    const int n   = blockIdx.z;         // 0..31
    const int tid = threadIdx.x;
    const int bh = tid >> 4;            // 0..15
    const int bw = tid & 15;            // 0..15

    const int id0 = 2 * bd, ih0 = 2 * bh, iw0 = 2 * bw;
    // clamped third indices: garbage propagates ONLY into y[..==3] which is
    // zeroed for edge threads below (those outputs are o==63, out of range).
    const int idc[3] = {id0, id0 + 1, min(id0 + 2, 31)};
    const int ihc[3] = {ih0, ih0 + 1, min(ih0 + 2, 31)};
    const int iw2    = min(iw0 + 2, 31);

    const float* xn = x + (size_t)n * (3 * 32768);

    float y[2][4][4][4] = {};

    #pragma unroll
    for (int ci = 0; ci < 3; ++ci) {
        const float* xc = xn + ci * 32768;

        // 3x3x3 patch, unconditional loads (float2 + scalar, 8B-aligned)
        float xl[3][3][3];
        #pragma unroll
        for (int dd = 0; dd < 3; ++dd) {
            #pragma unroll
            for (int hh = 0; hh < 3; ++hh) {
                const int ro = (idc[dd] * 32 + ihc[hh]) * 32;
                const float2 f2 = *reinterpret_cast<const float2*>(xc + ro + iw0);
                xl[dd][hh][0] = f2.x;
                xl[dd][hh][1] = f2.y;
                xl[dd][hh][2] = xc[ro + iw2];
            }
        }

        #pragma unroll
        for (int c2 = 0; c2 < 2; ++c2) {
            // weights uniform across block -> scalar loads
            const float* wp = w + ((size_t)ci * C_OUT + (2 * cop + c2)) * 27;
            float wl[27];
            #pragma unroll
            for (int k = 0; k < 27; ++k) wl[k] = wp[k];

            #pragma unroll
            for (int od = 0; od < 4; ++od) {
                #pragma unroll
                for (int pd = 0; pd < NPAIR[od]; ++pd) {
                    const int kd = PK[od][pd], idd = PI[od][pd];
                    #pragma unroll
                    for (int oh = 0; oh < 4; ++oh) {
                        #pragma unroll
                        for (int ph = 0; ph < NPAIR[oh]; ++ph) {
                            const int kh = PK[oh][ph], ihh = PI[oh][ph];
                            #pragma unroll
                            for (int ow = 0; ow < 4; ++ow) {
                                #pragma unroll
                                for (int pw = 0; pw < NPAIR[ow]; ++pw) {
                                    const int kw = PK[ow][pw], iww = PI[ow][pw];
                                    y[c2][od][oh][ow] = fmaf(wl[kd * 9 + kh * 3 + kw],
                                                             xl[idd][ihh][iww],
                                                             y[c2][od][oh][ow]);
                                }
                            }
                        }
                    }
                }
            }
        }
    }

    // zero invalid (o==63) elements: also kills clamp garbage before stats
    const bool ed = (bd == 15), eh = (bh == 15), ew = (bw == 15);
    if (ed) {
        #pragma unroll
        for (int c2 = 0; c2 < 2; ++c2)
            #pragma unroll
            for (int oh = 0; oh < 4; ++oh)
                #pragma unroll
                for (int ow = 0; ow < 4; ++ow) y[c2][3][oh][ow] = 0.0f;
    }
    if (eh) {
        #pragma unroll
        for (int c2 = 0; c2 < 2; ++c2)
            #pragma unroll
            for (int od = 0; od < 4; ++od)
                #pragma unroll
                for (int ow = 0; ow < 4; ++ow) y[c2][od][3][ow] = 0.0f;
    }
    if (ew) {
        #pragma unroll
        for (int c2 = 0; c2 < 2; ++c2)
            #pragma unroll
            for (int od = 0; od < 4; ++od)
                #pragma unroll
                for (int oh = 0; oh < 4; ++oh) y[c2][od][oh][3] = 0.0f;
    }

    // stats: plain sums (no masks)
    float s_sum[2] = {0.0f, 0.0f}, s_sq[2] = {0.0f, 0.0f};
    #pragma unroll
    for (int c2 = 0; c2 < 2; ++c2)
        #pragma unroll
        for (int od = 0; od < 4; ++od)
            #pragma unroll
            for (int oh = 0; oh < 4; ++oh)
                #pragma unroll
                for (int ow = 0; ow < 4; ++ow) {
                    const float v = y[c2][od][oh][ow];
                    s_sum[c2] += v;
                    s_sq[c2]   = fmaf(v, v, s_sq[c2]);
                }

    // pooled output (interior blocks only; all 64 voxels valid there)
    if (!ed && !eh && !ew) {
        #pragma unroll
        for (int c2 = 0; c2 < 2; ++c2) {
            const int co = 2 * cop + c2;
            const int oidx = ((((n * C_OUT) + co) * P_OUT + bd) * P_OUT + bh) * P_OUT + bw;
            pool[oidx] = s_sum[c2];
        }
    }

    // block reduction: wave butterfly + LDS across 4 waves
    float r0 = s_sum[0], r1 = s_sum[1], q0 = s_sq[0], q1 = s_sq[1];
    #pragma unroll
    for (int m = 1; m < 64; m <<= 1) {
        r0 += __shfl_xor(r0, m, 64);
        r1 += __shfl_xor(r1, m, 64);
        q0 += __shfl_xor(q0, m, 64);
        q1 += __shfl_xor(q1, m, 64);
    }
    __shared__ float red[16];
    const int wave = tid >> 6, lane = tid & 63;
    if (lane == 0) {
        red[wave] = r0; red[4 + wave] = r1;
        red[8 + wave] = q0; red[12 + wave] = q1;
    }
    __syncthreads();
    if (tid == 0) {
        const float ts0 = red[0] + red[1] + red[2] + red[3];
        const float ts1 = red[4] + red[5] + red[6] + red[7];
        const float tq0 = red[8] + red[9] + red[10] + red[11];
        const float tq1 = red[12] + red[13] + red[14] + red[15];
        const int co0 = 2 * cop, co1 = co0 + 1;
        const int p0 = (co0 * N_BATCH + n) * 16 + bd;   // [co][n][bd]
        const int p1 = (co1 * N_BATCH + n) * 16 + bd;
        partials[p0] = ts0;        partials[p1] = ts1;
        partials[8192 + p0] = tq0; partials[8192 + p1] = tq1;
    }
}

__global__ __launch_bounds__(256) void finalize_stats(
    const float* __restrict__ partials,  // ws
    const float* __restrict__ gamma,
    const float* __restrict__ beta,
    float* __restrict__ ab)              // ws + 16384: a[16], b[16]
{
    const int c = blockIdx.x;            // 0..15
    const int tid = threadIdx.x;         // 256
    float s = 0.0f, q = 0.0f;
    #pragma unroll
    for (int j = tid; j < 512; j += 256) {
        s += partials[c * 512 + j];
        q += partials[8192 + c * 512 + j];
    }
    #pragma unroll
    for (int m = 1; m < 64; m <<= 1) {
        s += __shfl_xor(s, m, 64);
        q += __shfl_xor(q, m, 64);
    }
    __shared__ float red[8];
    const int wave = tid >> 6, lane = tid & 63;
    if (lane == 0) { red[wave] = s; red[4 + wave] = q; }
    __syncthreads();
    if (tid == 0) {
        const float ts = red[0] + red[1] + red[2] + red[3];
        const float tq = red[4] + red[5] + red[6] + red[7];
        const float mean = ts / COUNT_Y;
        const float var  = tq / COUNT_Y - mean * mean;
        const float invg = rsqrtf(var + 1e-5f) * gamma[c];
        ab[c]      = invg * (1.0f / 64.0f);
        ab[16 + c] = beta[c] - mean * invg;
    }
}

__global__ __launch_bounds__(256) void apply_norm(
    float* __restrict__ out, const float* __restrict__ ab)
{
    const int base = (blockIdx.x * 256 + threadIdx.x) * 4;
    if (base >= TOTAL_OUT) return;
    float4 v = *reinterpret_cast<float4*>(out + base);
    float r[4] = {v.x, v.y, v.z, v.w};
    #pragma unroll
    for (int j = 0; j < 4; ++j) {
        const int c = ((base + j) / (P_OUT * P_OUT * P_OUT)) & 15;
        r[j] = fmaf(r[j], ab[c], ab[16 + c]);
    }
    *reinterpret_cast<float4*>(out + base) = make_float4(r[0], r[1], r[2], r[3]);
}

extern "C" void kernel_launch(void* const* d_in, const int* in_sizes, int n_in,
                              void* d_out, int out_size, void* d_ws, size_t ws_size,
                              hipStream_t stream) {
    const float* x     = (const float*)d_in[0];
    const float* w     = (const float*)d_in[1];
    const float* gamma = (const float*)d_in[2];
    const float* beta  = (const float*)d_in[3];
    float* out = (float*)d_out;
    float* ws  = (float*)d_ws;
    // ws layout (floats): [0,8192) sums, [8192,16384) sumsq, [16384,16416) a,b

    dim3 g1(16, 8, 32);   // bd, co-pair, n
    convt_pool_stats<<<g1, 256, 0, stream>>>(x, w, out, ws);
    finalize_stats<<<16, 256, 0, stream>>>(ws, gamma, beta, ws + 16384);

    const int nv4 = TOTAL_OUT / 4;  // 432,000
    apply_norm<<<(nv4 + 255) / 256, 256, 0, stream>>>(out, ws + 16384);
}